// Round 3
// baseline (257.528 us; speedup 1.0000x reference)
//
#include <hip/hip_runtime.h>
#include <hip/hip_bf16.h>
#include <math.h>

typedef __attribute__((ext_vector_type(8))) short short8;
typedef __attribute__((ext_vector_type(4))) short short4v;
typedef __attribute__((ext_vector_type(4))) float f32x4;
typedef __attribute__((ext_vector_type(2))) float f32x2;

__device__ __forceinline__ float bs2f(short s){
    union { unsigned u; float f; } x; x.u = ((unsigned)(unsigned short)s) << 16; return x.f;
}
__device__ __forceinline__ short f2bs(float f){
    union { float f; unsigned u; } x; x.f = f;
    unsigned r = x.u + 0x7fff + ((x.u >> 16) & 1);   // round-nearest-even
    return (short)(r >> 16);
}
__device__ __forceinline__ f32x2 up2(unsigned u){   // unpack 2 bf16 -> float2
    union { unsigned u; float f; } lo, hi;
    lo.u = u << 16; hi.u = u & 0xffff0000u;
    f32x2 r; r.x = lo.f; r.y = hi.f; return r;
}
__device__ __forceinline__ unsigned pk2rn(float lo, float hi){  // RNE pack
    __hip_bfloat162 h = __float22bfloat162_rn(make_float2(lo, hi));
    union { __hip_bfloat162 h; unsigned u; } cv; cv.h = h; return cv.u;
}
__device__ __forceinline__ void gl2lds16(const void* g, void* l){
    __builtin_amdgcn_global_load_lds(
        (const __attribute__((address_space(1))) void*)g,
        (__attribute__((address_space(3))) void*)l, 16, 0, 0);
}
__device__ __forceinline__ void hard_barrier(){
    __builtin_amdgcn_sched_barrier(0);
    __builtin_amdgcn_s_barrier();
    __builtin_amdgcn_sched_barrier(0);
}
// barrier that drains ONLY LDS ops (keeps global register-loads in flight)
__device__ __forceinline__ void lds_barrier(){
    __builtin_amdgcn_sched_barrier(0);
    asm volatile("s_waitcnt lgkmcnt(0)" ::: "memory");
    __builtin_amdgcn_s_barrier();
    __builtin_amdgcn_sched_barrier(0);
}

// Xpad[b][y][x][c]: y,x in [0,66), c in [0,512). Interior (y=h+1,x=w+1).
// c<256: flipped feature (= feature[b][c][h][63-w]); c>=256: proj.
#define XPB ((size_t)66*66*512)

// LDS k-quad XOR swizzle (B tiles): LDS quad p of row r holds global quad
// p^((r>>1)&3); fragment read for (row ln, quad q) uses LDS quad q^((ln>>1)&3).

// ---------------- prep: BN folding + weight transposes + Xpad halo zero ------
// grid 9249 x 256
__global__ void k_prep(const float* __restrict__ p1_w, const float* __restrict__ p1_b,
                       const float* __restrict__ bn1_g, const float* __restrict__ bn1_b,
                       const float* __restrict__ bn1_m, const float* __restrict__ bn1_v,
                       const float* __restrict__ off_w,
                       const float* __restrict__ dcn_w, const float* __restrict__ dcn_b,
                       const float* __restrict__ bn2_g, const float* __restrict__ bn2_b,
                       const float* __restrict__ bn2_m, const float* __restrict__ bn2_v,
                       short* __restrict__ p1_wb, short* __restrict__ Woffb,
                       short* __restrict__ Wbf,
                       float* __restrict__ bias1f, float* __restrict__ inv2f,
                       float* __restrict__ bias2f, unsigned* __restrict__ XpadU)
{
    int blk = blockIdx.x, t = threadIdx.x;
    if (blk == 0) {
        float inv1 = bn1_g[t] / sqrtf(bn1_v[t] + 1e-5f);
        bias1f[t] = p1_b[t] * inv1 + bn1_b[t] - bn1_m[t] * inv1;
        float inv2 = bn2_g[t] / sqrtf(bn2_v[t] + 1e-5f);
        inv2f[t] = inv2;
        bias2f[t] = dcn_b[t] * inv2 + bn2_b[t] - bn2_m[t] * inv2;
    } else if (blk <= 256) {
        int ci = blk - 1;
        float inv1 = bn1_g[t] / sqrtf(bn1_v[t] + 1e-5f);
        p1_wb[t*256 + ci] = f2bs(p1_w[t*256 + ci] * inv1);   // [o][ci], bn1 folded
    } else if (blk <= 2560) {
        int ck = blk - 257;                             // ck = c*9+tap (original order)
        int c = ck / 9, tap = ck % 9;
        Wbf[t*2304 + tap*256 + c] = f2bs(dcn_w[t*2304 + ck]);  // [o][tap*256+c]
    } else if (blk <= 7168) {
        int e = blk - 2561;                             // e = tap*512+ci (new K order)
        if (t < 32) {
            int tap = e >> 9, ci = e & 511;
            float v = off_w[((t < 27) ? t : 0)*4608 + ci*9 + tap];
            Woffb[t*4608 + e] = (t < 27) ? f2bs(v) : (short)0;  // [oc pad32][tap*512+ci]
        }
    } else {
        int hb = blk - 7169;                            // halo zero, 260 cells/b
        int b = hb / 260, i = hb % 260;
        int y, x;
        if (i < 66)       { y = 0;  x = i; }
        else if (i < 132) { y = 65; x = i - 66; }
        else { int j = i - 132; y = 1 + (j >> 1); x = (j & 1) * 65; }
        XpadU[((size_t)(b*66 + y)*66 + x)*256 + t] = 0u;
    }
}

// ---------------- transpose+flip -> Xpad flip half (bf16, channels-last) -----
// grid 2048 x 256  (8 b * 64 h * 4 c-groups)
__global__ void k_featT(const float* __restrict__ feature, short* __restrict__ Xpad)
{
    __shared__ float tile[64][65];
    int bb = blockIdx.x;
    int cg = bb & 3, h = (bb >> 2) & 63, b = bb >> 8;
    int c0 = cg * 64;
    int t = threadIdx.x;
    int lw = t & 63, li = t >> 6;
    #pragma unroll
    for (int j = 0; j < 16; ++j) {
        int cl = j*4 + li;
        tile[cl][63 - lw] = feature[((b*256 + c0 + cl)*64 + h)*64 + lw];
    }
    __syncthreads();
    #pragma unroll
    for (int j = 0; j < 16; ++j) {
        int wl = j*4 + li;
        Xpad[((size_t)(b*66 + h+1)*66 + (wl+1))*512 + c0 + lw] = f2bs(tile[lw][wl]);
    }
}

// ---------------- proj via MFMA: M=256(o) N=64(pos=one (b,h) row) K=256 -------
// grid 512 x 512 thr (8 waves, m-strip 32/wave); writes Xpad proj half
__global__ __launch_bounds__(512, 4) void k_projm(
    short* Xpad, const short* __restrict__ p1_wb, const float* __restrict__ bias1f)
{
    __shared__ short Ash[256*32];   // 16 KB [o][32k]
    __shared__ short Bsh[64*32];    //  4 KB [x][32k]
    int bid = blockIdx.x;
    int b = bid >> 6, h = bid & 63;
    int t = threadIdx.x;
    int lane = t & 63, w = t >> 6;
    int ln = lane & 15, q = lane >> 4;
    int r16 = lane >> 2;
    int sq  = (lane & 3) ^ ((lane >> 3) & 3);       // staging swizzled quad
    int rq  = (q ^ ((ln >> 1) & 3)) * 8;            // read swizzled quad offset
    size_t rowbase = (size_t)(b*66 + h + 1)*66;

    f32x4 acc[2][4] = {};
    for (int kt = 0; kt < 8; ++kt) {
        int kcol = kt*32 + sq*8;
        #pragma unroll
        for (int i = 0; i < 2; ++i) {
            int row = w*32 + i*16 + r16;
            gl2lds16(p1_wb + (size_t)row*256 + kcol, Ash + (w*32 + i*16)*32);
        }
        if (w < 4) {
            int x = w*16 + r16;                       // output w-coord
            gl2lds16(Xpad + (rowbase + (64 - x))*512 + kcol, Bsh + (w*16)*32);
        }
        __syncthreads();
        short8 af[2], bfr[4];
        #pragma unroll
        for (int i = 0; i < 2; ++i)
            af[i] = *(const short8*)&Ash[(w*32 + i*16 + ln)*32 + rq];
        #pragma unroll
        for (int j = 0; j < 4; ++j)
            bfr[j] = *(const short8*)&Bsh[(j*16 + ln)*32 + rq];
        #pragma unroll
        for (int i = 0; i < 2; ++i)
            #pragma unroll
            for (int j = 0; j < 4; ++j)
                acc[i][j] = __builtin_amdgcn_mfma_f32_16x16x32_bf16(af[i], bfr[j], acc[i][j], 0, 0, 0);
        __syncthreads();
    }
    #pragma unroll
    for (int i = 0; i < 2; ++i) {
        int ob = w*32 + i*16 + q*4;
        #pragma unroll
        for (int j = 0; j < 4; ++j) {
            int x = j*16 + ln;
            size_t xb = (rowbase + x + 1)*512 + 256 + ob;
            short4v st;
            st.x = f2bs(acc[i][j][0] + bias1f[ob]);
            st.y = f2bs(acc[i][j][1] + bias1f[ob+1]);
            st.z = f2bs(acc[i][j][2] + bias1f[ob+2]);
            st.w = f2bs(acc[i][j][3] + bias1f[ob+3]);
            *(short4v*)&Xpad[xb] = st;
        }
    }
}

// ---------------- offset conv via MFMA: M=32(27 oc) N=64(x) K=4608 ------------
// grid 512 ((b,h) rows) x 512 thr (8 waves: 2m x 4n); BK=128 as 4 stride-32
// sub-chunks per barrier window (36 iters, 4 MFMA/wave/window)  [R1 version]
__global__ __launch_bounds__(512, 4) void k_offm(
    const short* __restrict__ Xpad, const short* __restrict__ Woffb,
    const float* __restrict__ off_b, float* __restrict__ offv)
{
    __shared__ short Ash[4][32*32];   //  8 KB [oc][32k] x4
    __shared__ short Bsh[4][64*32];   // 16 KB [x][32k] x4
    int bid = blockIdx.x;
    int b = bid >> 6, h = bid & 63;
    int t = threadIdx.x;
    int lane = t & 63, w = t >> 6;
    int ln = lane & 15, q = lane >> 4;
    int wr = w >> 2, wc = w & 3;
    int r16 = lane >> 2;
    int sq  = (lane & 3) ^ ((lane >> 3) & 3);
    int rq  = (q ^ ((ln >> 1) & 3)) * 8;
    const short* xb = Xpad + (size_t)b*XPB;

    f32x4 acc = {};
    for (int it = 0; it < 36; ++it) {
        int tap = it >> 2, c0 = (it & 3) << 7;    // 128-ch chunk within tap
        int dy = tap/3 - 1, dx = tap%3 - 1;
        #pragma unroll
        for (int s = 0; s < 4; ++s) {
            int cc = c0 + s*32 + sq*8;
            if (w < 4) {                           // B rows x = w*16..+16
                int row = w*16 + r16;
                const short* gB = xb + ((size_t)(h + 1 + dy)*66 + (row + dx + 1))*512 + cc;
                gl2lds16(gB, &Bsh[s][(w*16)*32]);
            } else if (w < 6) {                    // A rows oc = (w-4)*16..+16
                int row = (w-4)*16 + r16;
                const short* gA = Woffb + (size_t)row*4608 + tap*512 + cc;
                gl2lds16(gA, &Ash[s][((w-4)*16)*32]);
            }
        }
        __syncthreads();
        #pragma unroll
        for (int s = 0; s < 4; ++s) {
            short8 af  = *(const short8*)&Ash[s][(wr*16 + ln)*32 + rq];
            short8 bfr = *(const short8*)&Bsh[s][(wc*16 + ln)*32 + rq];
            acc = __builtin_amdgcn_mfma_f32_16x16x32_bf16(af, bfr, acc, 0, 0, 0);
        }
        __syncthreads();
    }
    int x = wc*16 + ln;
    #pragma unroll
    for (int r = 0; r < 4; ++r) {
        int oc = wr*16 + q*4 + r;
        if (oc < 27)
            offv[((b*27 + oc)*64 + h)*64 + x] = acc[r] + off_b[oc];
    }
}

// ---------------- fused sample + dcn GEMM: M=256(o) N=64(pos) K=2304 ---------
// grid 512 (bid = h*8 + b, XCD-affine b) x 512 thr (8 waves, m-strip 32).
// A (Wbf) is loaded GLOBAL->REGISTER directly in MFMA fragment layout
// (lane(ln,q) reads row strip+ln, k-quad q as one dwordx4), double-buffered --
// no A LDS, no manual vmcnt (compiler auto-counts register loads).
// B (masked bilinear im2col) is blended in-register from Xpad gathers and
// ds_written to a double-buffered 16 KB Bsh -> ONE lds-only barrier/window.
// In-flight global loads (gathers + A) ride across barriers untouched.
__global__ __launch_bounds__(512, 3) void k_gemm(
    const short* __restrict__ Xpad,   // flip half: gathers; proj half: residual
    const short* __restrict__ Wbf,    // [256][2304] bf16
    const float* __restrict__ offv,   // [b][27][64][64] offsets+mask logits
    const float* __restrict__ inv2f, const float* __restrict__ bias2f,
    float* __restrict__ out)
{
    __shared__ __align__(16) short Bsh[2][2][64*32]; // 16 KB [buf][s][pos][32k]
    __shared__ unsigned c_pk[576];                   // 2.25 KB cell|sx<<20|sy<<21
    __shared__ float c_w[576*4];                     // 9 KB mask-scaled bilinear w
    int bid = blockIdx.x;
    int b = bid & 7, h = bid >> 3;                   // XCD-affine b
    int t = threadIdx.x;
    int lane = t & 63, w = t >> 6;
    int ln = lane & 15, q = lane >> 4;
    int rq  = (q ^ ((ln >> 1) & 3)) * 8;

    // ---- sampling metadata: 64 positions x 9 taps ----
    for (int e = t; e < 576; e += 512) {
        int p = e / 9, k = e % 9;
        int base = (b*27)*4096 + h*64 + p;
        float dy = offv[base + k*4096];
        float dx = offv[base + (9+k)*4096];
        float ms = offv[base + (18+k)*4096];
        ms = 1.f / (1.f + expf(-ms));
        float py = (float)h + (float)(k/3 - 1) + dy;
        float px = (float)p + (float)(k%3 - 1) + dx;
        float y0f = floorf(py), x0f = floorf(px);
        float wy = py - y0f, wx = px - x0f;
        int y0 = (int)y0f, x0 = (int)x0f;
        int y1 = y0 + 1, x1 = x0 + 1;
        float vy0 = (y0 >= 0 && y0 < 64) ? 1.f : 0.f;
        float vy1 = (y1 >= 0 && y1 < 64) ? 1.f : 0.f;
        float vx0 = (x0 >= 0 && x0 < 64) ? 1.f : 0.f;
        float vx1 = (x1 >= 0 && x1 < 64) ? 1.f : 0.f;
        int y0c = min(max(y0,0),63), y1c = min(max(y1,0),63);
        int x0c = min(max(x0,0),63), x1c = min(max(x1,0),63);
        unsigned cell = (unsigned)(((y0c+1)*66 + x0c+1)*128);   // uint2 units < 2^20
        unsigned sx = (x1c != x0c) ? 1u : 0u;
        unsigned sy = (y1c != y0c) ? 1u : 0u;
        c_pk[e] = cell | (sx << 20) | (sy << 21);
        c_w[e*4+0] = ms * (1.f-wy)*(1.f-wx) * vy0*vx0;
        c_w[e*4+1] = ms * (1.f-wy)*wx       * vy0*vx1;
        c_w[e*4+2] = ms * wy*(1.f-wx)       * vy1*vx0;
        c_w[e*4+3] = ms * wy*wx             * vy1*vx1;
    }
    __syncthreads();

    const uint2* fT = (const uint2*)Xpad + (size_t)b*(XPB/4);
    int pr = t >> 3;                    // B row (position) this thread fills
    int jo = t & 7;                     // channel octet within 64-col window
    int pe9 = pr*9;
    // swizzled ds_write target (within chosen buf/s): row pr, quad (jo&3)^swz
    int boff = pr*32 + (((jo & 3) ^ ((pr >> 1) & 3)) << 3);
    int bs_half = jo >> 2;
    const short* arow = Wbf + (size_t)(w*32 + ln)*2304 + q*8;  // i adds 16 rows

    f32x4 acc[2][4] = {};
    uint4 U[4], V[4];
    short8 A0[2][2], A1[2][2];          // [s][i] fragment regs, double-buffered

    auto GATHER = [&](int win, uint4 (&dst)[4]) {
        unsigned pw = c_pk[pe9 + (win >> 2)];
        int o00 = pw & 0xFFFFF;
        int dxs = (pw >> 13) & 128;                            // sx*128
        int dys = ((pw >> 8) & 0x2000) | ((pw >> 13) & 0x100); // sy*8448
        int cin = ((win & 3) << 4) + jo*2;
        const uint2* p0 = fT + (o00 + cin);
        dst[0] = *(const uint4*)(p0);
        dst[1] = *(const uint4*)(p0 + dxs);
        dst[2] = *(const uint4*)(p0 + dys);
        dst[3] = *(const uint4*)(p0 + dys + dxs);
    };
    auto ALOAD = [&](int kc, short8 (&af)[2][2]) {
        #pragma unroll
        for (int s = 0; s < 2; ++s)
            #pragma unroll
            for (int i = 0; i < 2; ++i)
                af[s][i] = *(const short8*)(arow + (size_t)i*16*2304 + kc*64 + s*32);
    };
    auto BLEND = [&](uint4 (&uc)[4], int tapW, int bufW) {
        const float4 cw = *(const float4*)&c_w[(pe9 + tapW)*4];
        f32x2 Wx; Wx.x = cw.x; Wx.y = cw.x;
        f32x2 Wy; Wy.x = cw.y; Wy.y = cw.y;
        f32x2 Wz; Wz.x = cw.z; Wz.y = cw.z;
        f32x2 Ww; Ww.x = cw.w; Ww.y = cw.w;
        f32x2 G0 = Wx*up2(uc[0].x) + Wy*up2(uc[1].x) + Wz*up2(uc[2].x) + Ww*up2(uc[3].x);
        f32x2 G1 = Wx*up2(uc[0].y) + Wy*up2(uc[1].y) + Wz*up2(uc[2].y) + Ww*up2(uc[3].y);
        f32x2 G2 = Wx*up2(uc[0].z) + Wy*up2(uc[1].z) + Wz*up2(uc[2].z) + Ww*up2(uc[3].z);
        f32x2 G3 = Wx*up2(uc[0].w) + Wy*up2(uc[1].w) + Wz*up2(uc[2].w) + Ww*up2(uc[3].w);
        uint4 pkv;
        pkv.x = pk2rn(G0.x, G0.y);
        pkv.y = pk2rn(G1.x, G1.y);
        pkv.z = pk2rn(G2.x, G2.y);
        pkv.w = pk2rn(G3.x, G3.y);
        *(uint4*)&Bsh[bufW][bs_half][boff] = pkv;
    };
    // enters: afC=A(kc), Bsh[bufR]=B(kc), Uc=G(kc+1). bufW = bufR^1 (literal).
    auto WIN = [&](int kc, int bufR, int bufW,
                   short8 (&afC)[2][2], short8 (&afN)[2][2],
                   uint4 (&Uc)[4], uint4 (&Un)[4]) {
        int kn = kc < 35 ? kc + 1 : 35;
        ALOAD(kn, afN);                    // 4 loads, in flight across barrier
        GATHER(kc < 34 ? kc + 2 : 35, Un); // 4 loads, in flight across barrier
        BLEND(Uc, kn >> 2, bufW);          // produce B(kn); waits only on Uc
        #pragma unroll
        for (int s = 0; s < 2; ++s) {
            short8 bfr[4];
            #pragma unroll
            for (int jj = 0; jj < 4; ++jj)
                bfr[jj] = *(const short8*)&Bsh[bufR][s][(jj*16 + ln)*32 + rq];
            #pragma unroll
            for (int i = 0; i < 2; ++i)
                #pragma unroll
                for (int jj = 0; jj < 4; ++jj)
                    acc[i][jj] = __builtin_amdgcn_mfma_f32_16x16x32_bf16(afC[s][i], bfr[jj], acc[i][jj], 0, 0, 0);
        }
        lds_barrier();                     // lgkmcnt(0) only; vmem stays in flight
    };

    // prologue: B(0) into buf0, A(0), G(1) in U
    GATHER(0, V);
    GATHER(1, U);
    ALOAD(0, A0);
    BLEND(V, 0, 0);
    lds_barrier();

    for (int kk = 0; kk < 18; ++kk) {
        WIN(kk*2,     0, 1, A0, A1, U, V);
        WIN(kk*2 + 1, 1, 0, A1, A0, V, U);
    }

    // epilogue: bn2 + residual(from Xpad proj half) + relu
    #pragma unroll
    for (int i = 0; i < 2; ++i) {
        int ob = w*32 + i*16 + q*4;
        #pragma unroll
        for (int jj = 0; jj < 4; ++jj) {
            int p = jj*16 + ln;
            size_t xb = ((size_t)(b*66 + h + 1)*66 + p + 1)*512 + 256 + ob;
            short4v prr = *(const short4v*)&Xpad[xb];
            #pragma unroll
            for (int r = 0; r < 4; ++r) {
                int o = ob + r;
                size_t idx = ((size_t)(b*256 + o))*4096 + h*64 + p;
                float rs = bs2f(((const short*)&prr)[r]);
                float v = rs + acc[i][jj][r]*inv2f[o] + bias2f[o];
                out[idx] = v < 0.f ? 0.f : v;   // NaN-propagating relu
            }
        }
    }
}

extern "C" void kernel_launch(void* const* d_in, const int* in_sizes, int n_in,
                              void* d_out, int out_size, void* d_ws, size_t ws_size,
                              hipStream_t stream)
{
    const float* feature = (const float*)d_in[0];
    const float* p1_w  = (const float*)d_in[1];
    const float* p1_b  = (const float*)d_in[2];
    const float* bn1_g = (const float*)d_in[3];
    const float* bn1_b = (const float*)d_in[4];
    const float* bn1_m = (const float*)d_in[5];
    const float* bn1_v = (const float*)d_in[6];
    const float* off_w = (const float*)d_in[7];
    const float* off_b = (const float*)d_in[8];
    const float* dcn_w = (const float*)d_in[9];
    const float* dcn_b = (const float*)d_in[10];
    const float* bn2_g = (const float*)d_in[11];
    const float* bn2_b = (const float*)d_in[12];
    const float* bn2_m = (const float*)d_in[13];
    const float* bn2_v = (const float*)d_in[14];

    // Workspace (float-slot offsets).
    float* ws = (float*)d_ws;
    short* Xpad   = (short*)ws;                 // 17,842,176 sh = 8,921,088 f
    float* offbuf = ws + 8921088;               //    884,736 f
    short* p1_wb  = (short*)(ws + 9805824);     //     65,536 sh = 32,768 f
    short* Woffb  = (short*)(ws + 9838592);     //    147,456 sh = 73,728 f
    short* Wbf    = (short*)(ws + 9912320);     //    589,824 sh = 294,912 f
    float* bias1f = ws + 10207232;              //        256
    float* inv2f  = ws + 10207488;              //        256
    float* bias2f = ws + 10207744;              //        256

    k_prep<<<9249, 256, 0, stream>>>(p1_w, p1_b, bn1_g, bn1_b, bn1_m, bn1_v,
                                     off_w, dcn_w, dcn_b, bn2_g, bn2_b, bn2_m, bn2_v,
                                     p1_wb, Woffb, Wbf, bias1f, inv2f, bias2f,
                                     (unsigned*)Xpad);
    k_featT<<<2048, 256, 0, stream>>>(feature, Xpad);
    k_projm<<<512, 512, 0, stream>>>(Xpad, p1_wb, bias1f);
    k_offm<<<512, 512, 0, stream>>>(Xpad, Woffb, off_b, offbuf);
    k_gemm<<<512, 512, 0, stream>>>(Xpad, Wbf, offbuf, inv2f, bias2f, (float*)d_out);
}

// Round 4
// 250.070 us; speedup vs baseline: 1.0298x; 1.0298x over previous
//
#include <hip/hip_runtime.h>
#include <hip/hip_bf16.h>
#include <math.h>

typedef __attribute__((ext_vector_type(8))) short short8;
typedef __attribute__((ext_vector_type(4))) short short4v;
typedef __attribute__((ext_vector_type(4))) float f32x4;
typedef __attribute__((ext_vector_type(2))) float f32x2;

__device__ __forceinline__ float bs2f(short s){
    union { unsigned u; float f; } x; x.u = ((unsigned)(unsigned short)s) << 16; return x.f;
}
__device__ __forceinline__ short f2bs(float f){
    union { float f; unsigned u; } x; x.f = f;
    unsigned r = x.u + 0x7fff + ((x.u >> 16) & 1);   // round-nearest-even
    return (short)(r >> 16);
}
__device__ __forceinline__ f32x2 up2(unsigned u){   // unpack 2 bf16 -> float2
    union { unsigned u; float f; } lo, hi;
    lo.u = u << 16; hi.u = u & 0xffff0000u;
    f32x2 r; r.x = lo.f; r.y = hi.f; return r;
}
__device__ __forceinline__ unsigned pk2rn(float lo, float hi){  // RNE pack
    __hip_bfloat162 h = __float22bfloat162_rn(make_float2(lo, hi));
    union { __hip_bfloat162 h; unsigned u; } cv; cv.h = h; return cv.u;
}
__device__ __forceinline__ void gl2lds16(const void* g, void* l){
    __builtin_amdgcn_global_load_lds(
        (const __attribute__((address_space(1))) void*)g,
        (__attribute__((address_space(3))) void*)l, 16, 0, 0);
}
__device__ __forceinline__ void hard_barrier(){
    __builtin_amdgcn_sched_barrier(0);
    __builtin_amdgcn_s_barrier();
    __builtin_amdgcn_sched_barrier(0);
}

// Xpad[b][y][x][c]: y,x in [0,66), c in [0,512). Interior (y=h+1,x=w+1).
// c<256: flipped feature (= feature[b][c][h][63-w]); c>=256: proj.
#define XPB ((size_t)66*66*512)

// LDS k-quad XOR swizzle: LDS quad p of row r holds global quad p^((r>>1)&3).
// Staging lane L (row L>>2, quad L&3) sources global quad (L&3)^((L>>3)&3);
// fragment read for (row ln, quad q) uses LDS quad q^((ln>>1)&3).

// ---------------- prep: BN folding + weight transposes + Xpad halo zero ------
// grid 9249 x 256
__global__ void k_prep(const float* __restrict__ p1_w, const float* __restrict__ p1_b,
                       const float* __restrict__ bn1_g, const float* __restrict__ bn1_b,
                       const float* __restrict__ bn1_m, const float* __restrict__ bn1_v,
                       const float* __restrict__ off_w,
                       const float* __restrict__ dcn_w, const float* __restrict__ dcn_b,
                       const float* __restrict__ bn2_g, const float* __restrict__ bn2_b,
                       const float* __restrict__ bn2_m, const float* __restrict__ bn2_v,
                       short* __restrict__ p1_wb, short* __restrict__ Woffb,
                       short* __restrict__ Wbf,
                       float* __restrict__ bias1f, float* __restrict__ inv2f,
                       float* __restrict__ bias2f, unsigned* __restrict__ XpadU)
{
    int blk = blockIdx.x, t = threadIdx.x;
    if (blk == 0) {
        float inv1 = bn1_g[t] / sqrtf(bn1_v[t] + 1e-5f);
        bias1f[t] = p1_b[t] * inv1 + bn1_b[t] - bn1_m[t] * inv1;
        float inv2 = bn2_g[t] / sqrtf(bn2_v[t] + 1e-5f);
        inv2f[t] = inv2;
        bias2f[t] = dcn_b[t] * inv2 + bn2_b[t] - bn2_m[t] * inv2;
    } else if (blk <= 256) {
        int ci = blk - 1;
        float inv1 = bn1_g[t] / sqrtf(bn1_v[t] + 1e-5f);
        p1_wb[t*256 + ci] = f2bs(p1_w[t*256 + ci] * inv1);   // [o][ci], bn1 folded
    } else if (blk <= 2560) {
        int ck = blk - 257;                             // ck = c*9+tap (original order)
        int c = ck / 9, tap = ck % 9;
        Wbf[t*2304 + tap*256 + c] = f2bs(dcn_w[t*2304 + ck]);  // [o][tap*256+c]
    } else if (blk <= 7168) {
        int e = blk - 2561;                             // e = tap*512+ci (new K order)
        if (t < 32) {
            int tap = e >> 9, ci = e & 511;
            float v = off_w[((t < 27) ? t : 0)*4608 + ci*9 + tap];
            Woffb[t*4608 + e] = (t < 27) ? f2bs(v) : (short)0;  // [oc pad32][tap*512+ci]
        }
    } else {
        int hb = blk - 7169;                            // halo zero, 260 cells/b
        int b = hb / 260, i = hb % 260;
        int y, x;
        if (i < 66)       { y = 0;  x = i; }
        else if (i < 132) { y = 65; x = i - 66; }
        else { int j = i - 132; y = 1 + (j >> 1); x = (j & 1) * 65; }
        XpadU[((size_t)(b*66 + y)*66 + x)*256 + t] = 0u;
    }
}

// ---------------- transpose+flip -> Xpad flip half (bf16, channels-last) -----
// grid 2048 x 256  (8 b * 64 h * 4 c-groups)
__global__ void k_featT(const float* __restrict__ feature, short* __restrict__ Xpad)
{
    __shared__ float tile[64][65];
    int bb = blockIdx.x;
    int cg = bb & 3, h = (bb >> 2) & 63, b = bb >> 8;
    int c0 = cg * 64;
    int t = threadIdx.x;
    int lw = t & 63, li = t >> 6;
    #pragma unroll
    for (int j = 0; j < 16; ++j) {
        int cl = j*4 + li;
        tile[cl][63 - lw] = feature[((b*256 + c0 + cl)*64 + h)*64 + lw];
    }
    __syncthreads();
    #pragma unroll
    for (int j = 0; j < 16; ++j) {
        int wl = j*4 + li;
        Xpad[((size_t)(b*66 + h+1)*66 + (wl+1))*512 + c0 + lw] = f2bs(tile[lw][wl]);
    }
}

// ---------------- proj via MFMA: M=256(o) N=64(pos=one (b,h) row) K=256 -------
// grid 512 x 512 thr (8 waves, m-strip 32/wave); writes Xpad proj half
__global__ __launch_bounds__(512, 4) void k_projm(
    short* Xpad, const short* __restrict__ p1_wb, const float* __restrict__ bias1f)
{
    __shared__ short Ash[256*32];   // 16 KB [o][32k]
    __shared__ short Bsh[64*32];    //  4 KB [x][32k]
    int bid = blockIdx.x;
    int b = bid >> 6, h = bid & 63;
    int t = threadIdx.x;
    int lane = t & 63, w = t >> 6;
    int ln = lane & 15, q = lane >> 4;
    int r16 = lane >> 2;
    int sq  = (lane & 3) ^ ((lane >> 3) & 3);       // staging swizzled quad
    int rq  = (q ^ ((ln >> 1) & 3)) * 8;            // read swizzled quad offset
    size_t rowbase = (size_t)(b*66 + h + 1)*66;

    f32x4 acc[2][4] = {};
    for (int kt = 0; kt < 8; ++kt) {
        int kcol = kt*32 + sq*8;
        #pragma unroll
        for (int i = 0; i < 2; ++i) {
            int row = w*32 + i*16 + r16;
            gl2lds16(p1_wb + (size_t)row*256 + kcol, Ash + (w*32 + i*16)*32);
        }
        if (w < 4) {
            int x = w*16 + r16;                       // output w-coord
            gl2lds16(Xpad + (rowbase + (64 - x))*512 + kcol, Bsh + (w*16)*32);
        }
        __syncthreads();
        short8 af[2], bfr[4];
        #pragma unroll
        for (int i = 0; i < 2; ++i)
            af[i] = *(const short8*)&Ash[(w*32 + i*16 + ln)*32 + rq];
        #pragma unroll
        for (int j = 0; j < 4; ++j)
            bfr[j] = *(const short8*)&Bsh[(j*16 + ln)*32 + rq];
        #pragma unroll
        for (int i = 0; i < 2; ++i)
            #pragma unroll
            for (int j = 0; j < 4; ++j)
                acc[i][j] = __builtin_amdgcn_mfma_f32_16x16x32_bf16(af[i], bfr[j], acc[i][j], 0, 0, 0);
        __syncthreads();
    }
    #pragma unroll
    for (int i = 0; i < 2; ++i) {
        int ob = w*32 + i*16 + q*4;
        #pragma unroll
        for (int j = 0; j < 4; ++j) {
            int x = j*16 + ln;
            size_t xb = (rowbase + x + 1)*512 + 256 + ob;
            short4v st;
            st.x = f2bs(acc[i][j][0] + bias1f[ob]);
            st.y = f2bs(acc[i][j][1] + bias1f[ob+1]);
            st.z = f2bs(acc[i][j][2] + bias1f[ob+2]);
            st.w = f2bs(acc[i][j][3] + bias1f[ob+3]);
            *(short4v*)&Xpad[xb] = st;
        }
    }
}

// ---------------- offset conv, wave-autonomous: M=32(27 oc) N=64(x) K=4608 ---
// grid 512 (bid = h*8 + b, XCD-affine) x 512 thr (8 waves). Each wave owns a
// K-slice of 18 x 32-k steps, loading A (Woffb) and B (Xpad, channels-last)
// fragments DIRECTLY global->register in MFMA layout (L2-resident), 8 MFMA
// per step, NO LDS staging and NO per-window barriers. One LDS reduction
// (8 partial 32x64 f32 tiles, stride padded to 36) + single barrier at end.
__global__ __launch_bounds__(512, 4) void k_offm(
    const short* __restrict__ Xpad, const short* __restrict__ Woffb,
    const float* __restrict__ off_b, float* __restrict__ offv)
{
    __shared__ float red[8][64][36];   // 73.7 KB partials [wave][x][oc pad36]
    int bid = blockIdx.x;
    int b = bid & 7, h = bid >> 3;
    int t = threadIdx.x;
    int lane = t & 63, g = t >> 6;     // g = wave = K-slice
    int ln = lane & 15, q = lane >> 4;
    const short* xb = Xpad + (size_t)b*XPB;

    f32x4 acc[2][4] = {};
    #pragma unroll 2
    for (int s8 = 0; s8 < 18; ++s8) {
        int s = g*18 + s8;                    // 144 steps of 32 k
        int tap = s >> 4, kc = s & 15;        // tap 0..8, 32-ch chunk 0..15
        int dy = tap/3 - 1, dx = tap%3 - 1;
        int co = kc*32 + q*8;                 // channel octet within concat 512
        short8 af[2], bfr[4];
        #pragma unroll
        for (int i = 0; i < 2; ++i)
            af[i] = *(const short8*)(Woffb + (size_t)(i*16 + ln)*4608 + tap*512 + co);
        #pragma unroll
        for (int j = 0; j < 4; ++j) {
            int x = j*16 + ln;
            bfr[j] = *(const short8*)(xb + ((size_t)(h + 1 + dy)*66 + (x + 1 + dx))*512 + co);
        }
        #pragma unroll
        for (int i = 0; i < 2; ++i)
            #pragma unroll
            for (int j = 0; j < 4; ++j)
                acc[i][j] = __builtin_amdgcn_mfma_f32_16x16x32_bf16(af[i], bfr[j], acc[i][j], 0, 0, 0);
    }

    // write partials: lane(ln,q) holds oc = i*16+q*4+r, x = j*16+ln
    #pragma unroll
    for (int i = 0; i < 2; ++i)
        #pragma unroll
        for (int j = 0; j < 4; ++j)
            *(f32x4*)&red[g][j*16 + ln][i*16 + q*4] = acc[i][j];
    __syncthreads();

    // reduce 8 partials: thread t -> x = t&63, oc quad o4 = t>>6
    int x = t & 63, o4 = (t >> 6) * 4;
    f32x4 sum = *(const f32x4*)&red[0][x][o4];
    #pragma unroll
    for (int gg = 1; gg < 8; ++gg)
        sum += *(const f32x4*)&red[gg][x][o4];
    #pragma unroll
    for (int r = 0; r < 4; ++r) {
        int oc = o4 + r;
        if (oc < 27)
            offv[((b*27 + oc)*64 + h)*64 + x] = sum[r] + off_b[oc];
    }
}

// ---------------- fused sample + dcn GEMM: M=256(o) N=64(pos) K=2304 ---------
// grid 512 (bid = h*8 + b, XCD-affine b) x 512 thr (8 waves, m-strip 32).
// [R2 version -- best measured 75.7 us] Counted-vmcnt pipeline: per window,
// issue 4 gl2lds16 (A) then 4 gather loads for window+1; blend's implicit
// wait drains the current gathers; `s_waitcnt vmcnt(4)` before the barrier
// drains only the A-stage, keeping next-window gathers in flight across the
// MFMA phase (U/V role-swap by unroll-2, no reg copies).
__global__ __launch_bounds__(512, 4) void k_gemm(
    const short* __restrict__ Xpad,   // flip half: gathers; proj half: residual
    const short* __restrict__ Wbf,    // [256][2304] bf16
    const float* __restrict__ offv,   // [b][27][64][64] offsets+mask logits
    const float* __restrict__ inv2f, const float* __restrict__ bias2f,
    float* __restrict__ out)
{
    __shared__ __align__(16) short Ash[2][256*32];   // 32 KB [o][32k] x2
    __shared__ __align__(16) short Bsh[2][64*32];    //  8 KB [pos][32k] x2
    __shared__ unsigned c_pk[576];                   // 2.25 KB cell|sx<<20|sy<<21
    __shared__ float c_w[576*4];                     // 9 KB mask-scaled bilinear w
    int bid = blockIdx.x;
    int b = bid & 7, h = bid >> 3;                   // XCD-affine b
    int t = threadIdx.x;
    int lane = t & 63, w = t >> 6;
    int ln = lane & 15, q = lane >> 4;
    int r16 = lane >> 2;
    int sq  = (lane & 3) ^ ((lane >> 3) & 3);
    int rq  = (q ^ ((ln >> 1) & 3)) * 8;

    // ---- sampling metadata: 64 positions x 9 taps ----
    for (int e = t; e < 576; e += 512) {
        int p = e / 9, k = e % 9;
        int base = (b*27)*4096 + h*64 + p;
        float dy = offv[base + k*4096];
        float dx = offv[base + (9+k)*4096];
        float ms = offv[base + (18+k)*4096];
        ms = 1.f / (1.f + expf(-ms));
        float py = (float)h + (float)(k/3 - 1) + dy;
        float px = (float)p + (float)(k%3 - 1) + dx;
        float y0f = floorf(py), x0f = floorf(px);
        float wy = py - y0f, wx = px - x0f;
        int y0 = (int)y0f, x0 = (int)x0f;
        int y1 = y0 + 1, x1 = x0 + 1;
        float vy0 = (y0 >= 0 && y0 < 64) ? 1.f : 0.f;
        float vy1 = (y1 >= 0 && y1 < 64) ? 1.f : 0.f;
        float vx0 = (x0 >= 0 && x0 < 64) ? 1.f : 0.f;
        float vx1 = (x1 >= 0 && x1 < 64) ? 1.f : 0.f;
        int y0c = min(max(y0,0),63), y1c = min(max(y1,0),63);
        int x0c = min(max(x0,0),63), x1c = min(max(x1,0),63);
        unsigned cell = (unsigned)(((y0c+1)*66 + x0c+1)*128);   // uint2 units < 2^20
        unsigned sx = (x1c != x0c) ? 1u : 0u;
        unsigned sy = (y1c != y0c) ? 1u : 0u;
        c_pk[e] = cell | (sx << 20) | (sy << 21);
        c_w[e*4+0] = ms * (1.f-wy)*(1.f-wx) * vy0*vx0;
        c_w[e*4+1] = ms * (1.f-wy)*wx       * vy0*vx1;
        c_w[e*4+2] = ms * wy*(1.f-wx)       * vy1*vx0;
        c_w[e*4+3] = ms * wy*wx             * vy1*vx1;
    }
    __syncthreads();

    const uint2* fT = (const uint2*)Xpad + (size_t)b*(XPB/4);
    int pr = t >> 3;                    // B row (position) this thread fills
    int jo = t & 7;                     // channel octet within 64-col window
    int pe9 = pr*9;
    short* bdst = &Bsh[jo >> 2][pr*32 + (((jo & 3) ^ ((pr >> 1) & 3)) << 3)];

    f32x4 acc[2][4] = {};
    uint4 U[4], V[4];

    auto GATHER = [&](int win, uint4 (&dst)[4]) {
        unsigned pw = c_pk[pe9 + (win >> 2)];
        int o00 = pw & 0xFFFFF;
        int dxs = (pw >> 13) & 128;                            // sx*128
        int dys = ((pw >> 8) & 0x2000) | ((pw >> 13) & 0x100); // sy*8448
        int cin = ((win & 3) << 4) + jo*2;
        const uint2* p0 = fT + (o00 + cin);
        dst[0] = *(const uint4*)(p0);
        dst[1] = *(const uint4*)(p0 + dxs);
        dst[2] = *(const uint4*)(p0 + dys);
        dst[3] = *(const uint4*)(p0 + dys + dxs);
    };

    auto WIN = [&](int kc2, uint4 (&uc)[4], uint4 (&vn)[4]) {
        int tap = kc2 >> 2;
        // A staging: exactly 4 gl2lds16 per wave (counted by vmcnt(4) below)
        #pragma unroll
        for (int s = 0; s < 2; ++s) {
            int kcol = (kc2*2 + s)*32 + sq*8;
            #pragma unroll
            for (int i = 0; i < 2; ++i) {
                int row = w*32 + i*16 + r16;
                gl2lds16(Wbf + (size_t)row*2304 + kcol, &Ash[s][(w*32 + i*16)*32]);
            }
        }
        __builtin_amdgcn_sched_barrier(0);   // pin order: A-stage before gathers
        GATHER(kc2 < 35 ? kc2 + 1 : 35, vn); // 4 loads, stay in flight over MFMA
        // blend current window -> Bsh (implicit wait drains uc only)
        const float4 cw = *(const float4*)&c_w[(pe9 + tap)*4];
        f32x2 Wx; Wx.x = cw.x; Wx.y = cw.x;
        f32x2 Wy; Wy.x = cw.y; Wy.y = cw.y;
        f32x2 Wz; Wz.x = cw.z; Wz.y = cw.z;
        f32x2 Ww; Ww.x = cw.w; Ww.y = cw.w;
        f32x2 G0 = Wx*up2(uc[0].x) + Wy*up2(uc[1].x) + Wz*up2(uc[2].x) + Ww*up2(uc[3].x);
        f32x2 G1 = Wx*up2(uc[0].y) + Wy*up2(uc[1].y) + Wz*up2(uc[2].y) + Ww*up2(uc[3].y);
        f32x2 G2 = Wx*up2(uc[0].z) + Wy*up2(uc[1].z) + Wz*up2(uc[2].z) + Ww*up2(uc[3].z);
        f32x2 G3 = Wx*up2(uc[0].w) + Wy*up2(uc[1].w) + Wz*up2(uc[2].w) + Ww*up2(uc[3].w);
        uint4 pkv;
        pkv.x = pk2rn(G0.x, G0.y);
        pkv.y = pk2rn(G1.x, G1.y);
        pkv.z = pk2rn(G2.x, G2.y);
        pkv.w = pk2rn(G3.x, G3.y);
        *(uint4*)bdst = pkv;
        // drain A-stage (4 oldest) + LDS writes; keep vn's 4 gathers in flight
        asm volatile("s_waitcnt vmcnt(4) lgkmcnt(0)" ::: "memory");
        hard_barrier();
        #pragma unroll
        for (int s = 0; s < 2; ++s) {
            short8 af[2], bfr[4];
            #pragma unroll
            for (int i = 0; i < 2; ++i)
                af[i] = *(const short8*)&Ash[s][(w*32 + i*16 + ln)*32 + rq];
            #pragma unroll
            for (int jj = 0; jj < 4; ++jj)
                bfr[jj] = *(const short8*)&Bsh[s][(jj*16 + ln)*32 + rq];
            #pragma unroll
            for (int i = 0; i < 2; ++i)
                #pragma unroll
                for (int jj = 0; jj < 4; ++jj)
                    acc[i][jj] = __builtin_amdgcn_mfma_f32_16x16x32_bf16(af[i], bfr[jj], acc[i][jj], 0, 0, 0);
        }
        hard_barrier();
    };

    GATHER(0, U);
    __builtin_amdgcn_sched_barrier(0);
    for (int kc2 = 0; kc2 < 36; kc2 += 2) {
        WIN(kc2, U, V);
        WIN(kc2 + 1, V, U);
    }

    // epilogue: bn2 + residual(from Xpad proj half) + relu
    #pragma unroll
    for (int i = 0; i < 2; ++i) {
        int ob = w*32 + i*16 + q*4;
        #pragma unroll
        for (int jj = 0; jj < 4; ++jj) {
            int p = jj*16 + ln;
            size_t xb = ((size_t)(b*66 + h + 1)*66 + p + 1)*512 + 256 + ob;
            short4v prr = *(const short4v*)&Xpad[xb];
            #pragma unroll
            for (int r = 0; r < 4; ++r) {
                int o = ob + r;
                size_t idx = ((size_t)(b*256 + o))*4096 + h*64 + p;
                float rs = bs2f(((const short*)&prr)[r]);
                float v = rs + acc[i][jj][r]*inv2f[o] + bias2f[o];
                out[idx] = v < 0.f ? 0.f : v;   // NaN-propagating relu
            }
        }
    }
}

extern "C" void kernel_launch(void* const* d_in, const int* in_sizes, int n_in,
                              void* d_out, int out_size, void* d_ws, size_t ws_size,
                              hipStream_t stream)
{
    const float* feature = (const float*)d_in[0];
    const float* p1_w  = (const float*)d_in[1];
    const float* p1_b  = (const float*)d_in[2];
    const float* bn1_g = (const float*)d_in[3];
    const float* bn1_b = (const float*)d_in[4];
    const float* bn1_m = (const float*)d_in[5];
    const float* bn1_v = (const float*)d_in[6];
    const float* off_w = (const float*)d_in[7];
    const float* off_b = (const float*)d_in[8];
    const float* dcn_w = (const float*)d_in[9];
    const float* dcn_b = (const float*)d_in[10];
    const float* bn2_g = (const float*)d_in[11];
    const float* bn2_b = (const float*)d_in[12];
    const float* bn2_m = (const float*)d_in[13];
    const float* bn2_v = (const float*)d_in[14];

    // Workspace (float-slot offsets).
    float* ws = (float*)d_ws;
    short* Xpad   = (short*)ws;                 // 17,842,176 sh = 8,921,088 f
    float* offbuf = ws + 8921088;               //    884,736 f
    short* p1_wb  = (short*)(ws + 9805824);     //     65,536 sh = 32,768 f
    short* Woffb  = (short*)(ws + 9838592);     //    147,456 sh = 73,728 f
    short* Wbf    = (short*)(ws + 9912320);     //    589,824 sh = 294,912 f
    float* bias1f = ws + 10207232;              //        256
    float* inv2f  = ws + 10207488;              //        256
    float* bias2f = ws + 10207744;              //        256

    k_prep<<<9249, 256, 0, stream>>>(p1_w, p1_b, bn1_g, bn1_b, bn1_m, bn1_v,
                                     off_w, dcn_w, dcn_b, bn2_g, bn2_b, bn2_m, bn2_v,
                                     p1_wb, Woffb, Wbf, bias1f, inv2f, bias2f,
                                     (unsigned*)Xpad);
    k_featT<<<2048, 256, 0, stream>>>(feature, Xpad);
    k_projm<<<512, 512, 0, stream>>>(Xpad, p1_wb, bias1f);
    k_offm<<<512, 512, 0, stream>>>(Xpad, Woffb, off_b, offbuf);
    k_gemm<<<512, 512, 0, stream>>>(Xpad, Wbf, offbuf, inv2f, bias2f, (float*)d_out);
}

// Round 5
// 218.928 us; speedup vs baseline: 1.1763x; 1.1422x over previous
//
#include <hip/hip_runtime.h>
#include <hip/hip_bf16.h>
#include <math.h>

typedef __attribute__((ext_vector_type(8))) short short8;
typedef __attribute__((ext_vector_type(4))) short short4v;
typedef __attribute__((ext_vector_type(4))) float f32x4;
typedef __attribute__((ext_vector_type(2))) float f32x2;

__device__ __forceinline__ float bs2f(short s){
    union { unsigned u; float f; } x; x.u = ((unsigned)(unsigned short)s) << 16; return x.f;
}
__device__ __forceinline__ short f2bs(float f){
    union { float f; unsigned u; } x; x.f = f;
    unsigned r = x.u + 0x7fff + ((x.u >> 16) & 1);   // round-nearest-even
    return (short)(r >> 16);
}
__device__ __forceinline__ f32x2 up2(unsigned u){   // unpack 2 bf16 -> float2
    union { unsigned u; float f; } lo, hi;
    lo.u = u << 16; hi.u = u & 0xffff0000u;
    f32x2 r; r.x = lo.f; r.y = hi.f; return r;
}
__device__ __forceinline__ unsigned pk2rn(float lo, float hi){  // RNE pack
    __hip_bfloat162 h = __float22bfloat162_rn(make_float2(lo, hi));
    union { __hip_bfloat162 h; unsigned u; } cv; cv.h = h; return cv.u;
}
__device__ __forceinline__ void gl2lds16(const void* g, void* l){
    __builtin_amdgcn_global_load_lds(
        (const __attribute__((address_space(1))) void*)g,
        (__attribute__((address_space(3))) void*)l, 16, 0, 0);
}
__device__ __forceinline__ void hard_barrier(){
    __builtin_amdgcn_sched_barrier(0);
    __builtin_amdgcn_s_barrier();
    __builtin_amdgcn_sched_barrier(0);
}

// Xpad[b][y][x][c]: y,x in [0,66), c in [0,512). Interior (y=h+1,x=w+1).
// c<256: flipped feature (= feature[b][c][h][63-w]); c>=256: proj.
#define XPB ((size_t)66*66*512)

// LDS k-quad XOR swizzle: LDS quad p of row r holds global quad p^((r>>1)&3).
// Staging lane L (row L>>2, quad L&3) sources global quad (L&3)^((L>>3)&3);
// fragment read for (row ln, quad q) uses LDS quad q^((ln>>1)&3).

// ---------------- prep: BN folding + weight transposes + Xpad halo zero ------
// grid 2625 x 256 -- all reads/writes coalesced (or stride-36B L2-resident)
__global__ void k_prep(const float* __restrict__ p1_w, const float* __restrict__ p1_b,
                       const float* __restrict__ bn1_g, const float* __restrict__ bn1_b,
                       const float* __restrict__ bn1_m, const float* __restrict__ bn1_v,
                       const float* __restrict__ off_w,
                       const float* __restrict__ dcn_w, const float* __restrict__ dcn_b,
                       const float* __restrict__ bn2_g, const float* __restrict__ bn2_b,
                       const float* __restrict__ bn2_m, const float* __restrict__ bn2_v,
                       short* __restrict__ p1_wb, short* __restrict__ Woffb,
                       short* __restrict__ Wbf,
                       float* __restrict__ bias1f, float* __restrict__ inv2f,
                       float* __restrict__ bias2f, unsigned* __restrict__ XpadU)
{
    int blk = blockIdx.x, t = threadIdx.x;
    if (blk == 0) {
        float inv1 = bn1_g[t] / sqrtf(bn1_v[t] + 1e-5f);
        bias1f[t] = p1_b[t] * inv1 + bn1_b[t] - bn1_m[t] * inv1;
        float inv2 = bn2_g[t] / sqrtf(bn2_v[t] + 1e-5f);
        inv2f[t] = inv2;
        bias2f[t] = dcn_b[t] * inv2 + bn2_b[t] - bn2_m[t] * inv2;
    } else if (blk <= 256) {                        // p1_wb row o (bn1 folded)
        int o = blk - 1;
        float inv1 = bn1_g[o] / sqrtf(bn1_v[o] + 1e-5f);
        p1_wb[o*256 + t] = f2bs(p1_w[o*256 + t] * inv1);
    } else if (blk <= 512) {                        // Wbf row o: [o][tap*256+c]
        int o = blk - 257;
        const float* src = dcn_w + (size_t)o*2304;  // [c*9+tap]
        #pragma unroll
        for (int j = 0; j < 9; ++j)                 // c = t, tap = j
            Wbf[(size_t)o*2304 + j*256 + t] = f2bs(src[t*9 + j]);
    } else if (blk <= 544) {                        // Woffb row oc: [oc][tap*512+ci]
        int oc = blk - 513;                         // 0..31 (pad to 32)
        if (oc < 27) {
            const float* src = off_w + (size_t)oc*4608;  // [ci*9+tap]
            #pragma unroll
            for (int j = 0; j < 18; ++j) {
                int e = j*256 + t, tap = e >> 9, ci = e & 511;
                Woffb[(size_t)oc*4608 + e] = f2bs(src[ci*9 + tap]);
            }
        } else {
            #pragma unroll
            for (int j = 0; j < 18; ++j)
                Woffb[(size_t)oc*4608 + j*256 + t] = 0;
        }
    } else {
        int hb = blk - 545;                         // halo zero, 260 cells/b
        int b = hb / 260, i = hb % 260;
        int y, x;
        if (i < 66)       { y = 0;  x = i; }
        else if (i < 132) { y = 65; x = i - 66; }
        else { int j = i - 132; y = 1 + (j >> 1); x = (j & 1) * 65; }
        XpadU[((size_t)(b*66 + y)*66 + x)*256 + t] = 0u;
    }
}

// ---------------- transpose+flip -> Xpad flip half (bf16, channels-last) -----
// grid 2048 x 256  (8 b * 64 h * 4 c-groups), XCD-affine b
__global__ void k_featT(const float* __restrict__ feature, short* __restrict__ Xpad)
{
    __shared__ float tile[64][65];
    int bb = blockIdx.x;
    int b = bb & 7, h = (bb >> 3) & 63, cg = bb >> 9;
    int c0 = cg * 64;
    int t = threadIdx.x;
    int lw = t & 63, li = t >> 6;
    #pragma unroll
    for (int j = 0; j < 16; ++j) {
        int cl = j*4 + li;
        tile[cl][63 - lw] = feature[((b*256 + c0 + cl)*64 + h)*64 + lw];
    }
    __syncthreads();
    #pragma unroll
    for (int j = 0; j < 16; ++j) {
        int wl = j*4 + li;
        Xpad[((size_t)(b*66 + h+1)*66 + (wl+1))*512 + c0 + lw] = f2bs(tile[lw][wl]);
    }
}

// ---------------- proj via MFMA: M=256(o) N=64(pos=one (b,h) row) K=256 -------
// grid 512 (bid = h*8 + b, XCD-affine) x 512 thr (8 waves, m-strip 32/wave)
__global__ __launch_bounds__(512, 4) void k_projm(
    short* Xpad, const short* __restrict__ p1_wb, const float* __restrict__ bias1f)
{
    __shared__ short Ash[256*32];   // 16 KB [o][32k]
    __shared__ short Bsh[64*32];    //  4 KB [x][32k]
    int bid = blockIdx.x;
    int b = bid & 7, h = bid >> 3;
    int t = threadIdx.x;
    int lane = t & 63, w = t >> 6;
    int ln = lane & 15, q = lane >> 4;
    int r16 = lane >> 2;
    int sq  = (lane & 3) ^ ((lane >> 3) & 3);       // staging swizzled quad
    int rq  = (q ^ ((ln >> 1) & 3)) * 8;            // read swizzled quad offset
    size_t rowbase = (size_t)(b*66 + h + 1)*66;

    f32x4 acc[2][4] = {};
    for (int kt = 0; kt < 8; ++kt) {
        int kcol = kt*32 + sq*8;
        #pragma unroll
        for (int i = 0; i < 2; ++i) {
            int row = w*32 + i*16 + r16;
            gl2lds16(p1_wb + (size_t)row*256 + kcol, Ash + (w*32 + i*16)*32);
        }
        if (w < 4) {
            int x = w*16 + r16;                       // output w-coord
            gl2lds16(Xpad + (rowbase + (64 - x))*512 + kcol, Bsh + (w*16)*32);
        }
        __syncthreads();
        short8 af[2], bfr[4];
        #pragma unroll
        for (int i = 0; i < 2; ++i)
            af[i] = *(const short8*)&Ash[(w*32 + i*16 + ln)*32 + rq];
        #pragma unroll
        for (int j = 0; j < 4; ++j)
            bfr[j] = *(const short8*)&Bsh[(j*16 + ln)*32 + rq];
        #pragma unroll
        for (int i = 0; i < 2; ++i)
            #pragma unroll
            for (int j = 0; j < 4; ++j)
                acc[i][j] = __builtin_amdgcn_mfma_f32_16x16x32_bf16(af[i], bfr[j], acc[i][j], 0, 0, 0);
        __syncthreads();
    }
    #pragma unroll
    for (int i = 0; i < 2; ++i) {
        int ob = w*32 + i*16 + q*4;
        #pragma unroll
        for (int j = 0; j < 4; ++j) {
            int x = j*16 + ln;
            size_t xb = (rowbase + x + 1)*512 + 256 + ob;
            short4v st;
            st.x = f2bs(acc[i][j][0] + bias1f[ob]);
            st.y = f2bs(acc[i][j][1] + bias1f[ob+1]);
            st.z = f2bs(acc[i][j][2] + bias1f[ob+2]);
            st.w = f2bs(acc[i][j][3] + bias1f[ob+3]);
            *(short4v*)&Xpad[xb] = st;
        }
    }
}

// ---------------- offset conv via MFMA: M=32(27 oc) N=64(x) K=4608 ------------
// grid 512 (bid = h*8 + b, XCD-affine) x 512 thr (8 waves: 2m x 4n).
// BK=256 as 8 stride-32 sub-chunks per barrier window: 18 windows (was 36),
// 8 MFMA/wave/window, LDS 48 KB (2 blocks/CU) -- halves the per-window
// barrier+drain fixed cost that dominated the R1 version.
__global__ __launch_bounds__(512, 4) void k_offm(
    const short* __restrict__ Xpad, const short* __restrict__ Woffb,
    const float* __restrict__ off_b, float* __restrict__ offv)
{
    __shared__ short Ash[8][32*32];   // 16 KB [oc][32k] x8
    __shared__ short Bsh[8][64*32];   // 32 KB [x][32k] x8
    int bid = blockIdx.x;
    int b = bid & 7, h = bid >> 3;
    int t = threadIdx.x;
    int lane = t & 63, w = t >> 6;
    int ln = lane & 15, q = lane >> 4;
    int wr = w >> 2, wc = w & 3;
    int r16 = lane >> 2;
    int sq  = (lane & 3) ^ ((lane >> 3) & 3);
    int rq  = (q ^ ((ln >> 1) & 3)) * 8;
    const short* xb = Xpad + (size_t)b*XPB;

    f32x4 acc = {};
    for (int it = 0; it < 18; ++it) {
        #pragma unroll
        for (int s = 0; s < 8; ++s) {
            int k = it*256 + s*32;                // 32-k sub-chunk (within one tap)
            int tap = k >> 9;
            int dy = tap/3 - 1, dx = tap%3 - 1;
            if (w < 4) {                           // B rows x = w*16..+16
                int row = w*16 + r16;
                const short* gB = xb + ((size_t)(h + 1 + dy)*66 + (row + dx + 1))*512
                                     + (k & 511) + sq*8;
                gl2lds16(gB, &Bsh[s][(w*16)*32]);
            } else if (w < 6) {                    // A rows oc = (w-4)*16..+16
                int row = (w-4)*16 + r16;
                const short* gA = Woffb + (size_t)row*4608 + k + sq*8;
                gl2lds16(gA, &Ash[s][((w-4)*16)*32]);
            }
        }
        __syncthreads();
        #pragma unroll
        for (int s = 0; s < 8; ++s) {
            short8 af  = *(const short8*)&Ash[s][(wr*16 + ln)*32 + rq];
            short8 bfr = *(const short8*)&Bsh[s][(wc*16 + ln)*32 + rq];
            acc = __builtin_amdgcn_mfma_f32_16x16x32_bf16(af, bfr, acc, 0, 0, 0);
        }
        __syncthreads();
    }
    int x = wc*16 + ln;
    #pragma unroll
    for (int r = 0; r < 4; ++r) {
        int oc = wr*16 + q*4 + r;
        if (oc < 27)
            offv[((b*27 + oc)*64 + h)*64 + x] = acc[r] + off_b[oc];
    }
}

// ---------------- fused sample + dcn GEMM: M=256(o) N=64(pos) K=2304 ---------
// grid 512 (bid = h*8 + b, XCD-affine b) x 512 thr (8 waves, m-strip 32).
// [R2 version -- best measured 74.5 us] Counted-vmcnt pipeline: per window,
// issue 4 gl2lds16 (A) then 4 gather loads for window+1; blend's implicit
// wait drains the current gathers; `s_waitcnt vmcnt(4)` before the barrier
// drains only the A-stage, keeping next-window gathers in flight across the
// MFMA phase (U/V role-swap by unroll-2, no reg copies).
__global__ __launch_bounds__(512, 4) void k_gemm(
    const short* __restrict__ Xpad,   // flip half: gathers; proj half: residual
    const short* __restrict__ Wbf,    // [256][2304] bf16
    const float* __restrict__ offv,   // [b][27][64][64] offsets+mask logits
    const float* __restrict__ inv2f, const float* __restrict__ bias2f,
    float* __restrict__ out)
{
    __shared__ __align__(16) short Ash[2][256*32];   // 32 KB [o][32k] x2
    __shared__ __align__(16) short Bsh[2][64*32];    //  8 KB [pos][32k] x2
    __shared__ unsigned c_pk[576];                   // 2.25 KB cell|sx<<20|sy<<21
    __shared__ float c_w[576*4];                     // 9 KB mask-scaled bilinear w
    int bid = blockIdx.x;
    int b = bid & 7, h = bid >> 3;                   // XCD-affine b
    int t = threadIdx.x;
    int lane = t & 63, w = t >> 6;
    int ln = lane & 15, q = lane >> 4;
    int r16 = lane >> 2;
    int sq  = (lane & 3) ^ ((lane >> 3) & 3);
    int rq  = (q ^ ((ln >> 1) & 3)) * 8;

    // ---- sampling metadata: 64 positions x 9 taps ----
    for (int e = t; e < 576; e += 512) {
        int p = e / 9, k = e % 9;
        int base = (b*27)*4096 + h*64 + p;
        float dy = offv[base + k*4096];
        float dx = offv[base + (9+k)*4096];
        float ms = offv[base + (18+k)*4096];
        ms = 1.f / (1.f + expf(-ms));
        float py = (float)h + (float)(k/3 - 1) + dy;
        float px = (float)p + (float)(k%3 - 1) + dx;
        float y0f = floorf(py), x0f = floorf(px);
        float wy = py - y0f, wx = px - x0f;
        int y0 = (int)y0f, x0 = (int)x0f;
        int y1 = y0 + 1, x1 = x0 + 1;
        float vy0 = (y0 >= 0 && y0 < 64) ? 1.f : 0.f;
        float vy1 = (y1 >= 0 && y1 < 64) ? 1.f : 0.f;
        float vx0 = (x0 >= 0 && x0 < 64) ? 1.f : 0.f;
        float vx1 = (x1 >= 0 && x1 < 64) ? 1.f : 0.f;
        int y0c = min(max(y0,0),63), y1c = min(max(y1,0),63);
        int x0c = min(max(x0,0),63), x1c = min(max(x1,0),63);
        unsigned cell = (unsigned)(((y0c+1)*66 + x0c+1)*128);   // uint2 units < 2^20
        unsigned sx = (x1c != x0c) ? 1u : 0u;
        unsigned sy = (y1c != y0c) ? 1u : 0u;
        c_pk[e] = cell | (sx << 20) | (sy << 21);
        c_w[e*4+0] = ms * (1.f-wy)*(1.f-wx) * vy0*vx0;
        c_w[e*4+1] = ms * (1.f-wy)*wx       * vy0*vx1;
        c_w[e*4+2] = ms * wy*(1.f-wx)       * vy1*vx0;
        c_w[e*4+3] = ms * wy*wx             * vy1*vx1;
    }
    __syncthreads();

    const uint2* fT = (const uint2*)Xpad + (size_t)b*(XPB/4);
    int pr = t >> 3;                    // B row (position) this thread fills
    int jo = t & 7;                     // channel octet within 64-col window
    int pe9 = pr*9;
    short* bdst = &Bsh[jo >> 2][pr*32 + (((jo & 3) ^ ((pr >> 1) & 3)) << 3)];

    f32x4 acc[2][4] = {};
    uint4 U[4], V[4];

    auto GATHER = [&](int win, uint4 (&dst)[4]) {
        unsigned pw = c_pk[pe9 + (win >> 2)];
        int o00 = pw & 0xFFFFF;
        int dxs = (pw >> 13) & 128;                            // sx*128
        int dys = ((pw >> 8) & 0x2000) | ((pw >> 13) & 0x100); // sy*8448
        int cin = ((win & 3) << 4) + jo*2;
        const uint2* p0 = fT + (o00 + cin);
        dst[0] = *(const uint4*)(p0);
        dst[1] = *(const uint4*)(p0 + dxs);
        dst[2] = *(const uint4*)(p0 + dys);
        dst[3] = *(const uint4*)(p0 + dys + dxs);
    };

    auto WIN = [&](int kc2, uint4 (&uc)[4], uint4 (&vn)[4]) {
        int tap = kc2 >> 2;
        // A staging: exactly 4 gl2lds16 per wave (counted by vmcnt(4) below)
        #pragma unroll
        for (int s = 0; s < 2; ++s) {
            int kcol = (kc2*2 + s)*32 + sq*8;
            #pragma unroll
            for (int i = 0; i < 2; ++i) {
                int row = w*32 + i*16 + r16;
                gl2lds16(Wbf + (size_t)row*2304 + kcol, &Ash[s][(w*32 + i*16)*32]);
            }
        }
        __builtin_amdgcn_sched_barrier(0);   // pin order: A-stage before gathers
        GATHER(kc2 < 35 ? kc2 + 1 : 35, vn); // 4 loads, stay in flight over MFMA
        // blend current window -> Bsh (implicit wait drains uc only)
        const float4 cw = *(const float4*)&c_w[(pe9 + tap)*4];
        f32x2 Wx; Wx.x = cw.x; Wx.y = cw.x;
        f32x2 Wy; Wy.x = cw.y; Wy.y = cw.y;
        f32x2 Wz; Wz.x = cw.z; Wz.y = cw.z;
        f32x2 Ww; Ww.x = cw.w; Ww.y = cw.w;
        f32x2 G0 = Wx*up2(uc[0].x) + Wy*up2(uc[1].x) + Wz*up2(uc[2].x) + Ww*up2(uc[3].x);
        f32x2 G1 = Wx*up2(uc[0].y) + Wy*up2(uc[1].y) + Wz*up2(uc[2].y) + Ww*up2(uc[3].y);
        f32x2 G2 = Wx*up2(uc[0].z) + Wy*up2(uc[1].z) + Wz*up2(uc[2].z) + Ww*up2(uc[3].z);
        f32x2 G3 = Wx*up2(uc[0].w) + Wy*up2(uc[1].w) + Wz*up2(uc[2].w) + Ww*up2(uc[3].w);
        uint4 pkv;
        pkv.x = pk2rn(G0.x, G0.y);
        pkv.y = pk2rn(G1.x, G1.y);
        pkv.z = pk2rn(G2.x, G2.y);
        pkv.w = pk2rn(G3.x, G3.y);
        *(uint4*)bdst = pkv;
        // drain A-stage (4 oldest) + LDS writes; keep vn's 4 gathers in flight
        asm volatile("s_waitcnt vmcnt(4) lgkmcnt(0)" ::: "memory");
        hard_barrier();
        #pragma unroll
        for (int s = 0; s < 2; ++s) {
            short8 af[2], bfr[4];
            #pragma unroll
            for (int i = 0; i < 2; ++i)
                af[i] = *(const short8*)&Ash[s][(w*32 + i*16 + ln)*32 + rq];
            #pragma unroll
            for (int jj = 0; jj < 4; ++jj)
                bfr[jj] = *(const short8*)&Bsh[s][(jj*16 + ln)*32 + rq];
            #pragma unroll
            for (int i = 0; i < 2; ++i)
                #pragma unroll
                for (int jj = 0; jj < 4; ++jj)
                    acc[i][jj] = __builtin_amdgcn_mfma_f32_16x16x32_bf16(af[i], bfr[jj], acc[i][jj], 0, 0, 0);
        }
        hard_barrier();
    };

    GATHER(0, U);
    __builtin_amdgcn_sched_barrier(0);
    for (int kc2 = 0; kc2 < 36; kc2 += 2) {
        WIN(kc2, U, V);
        WIN(kc2 + 1, V, U);
    }

    // epilogue: bn2 + residual(from Xpad proj half) + relu
    #pragma unroll
    for (int i = 0; i < 2; ++i) {
        int ob = w*32 + i*16 + q*4;
        #pragma unroll
        for (int jj = 0; jj < 4; ++jj) {
            int p = jj*16 + ln;
            size_t xb = ((size_t)(b*66 + h + 1)*66 + p + 1)*512 + 256 + ob;
            short4v prr = *(const short4v*)&Xpad[xb];
            #pragma unroll
            for (int r = 0; r < 4; ++r) {
                int o = ob + r;
                size_t idx = ((size_t)(b*256 + o))*4096 + h*64 + p;
                float rs = bs2f(((const short*)&prr)[r]);
                float v = rs + acc[i][jj][r]*inv2f[o] + bias2f[o];
                out[idx] = v < 0.f ? 0.f : v;   // NaN-propagating relu
            }
        }
    }
}

extern "C" void kernel_launch(void* const* d_in, const int* in_sizes, int n_in,
                              void* d_out, int out_size, void* d_ws, size_t ws_size,
                              hipStream_t stream)
{
    const float* feature = (const float*)d_in[0];
    const float* p1_w  = (const float*)d_in[1];
    const float* p1_b  = (const float*)d_in[2];
    const float* bn1_g = (const float*)d_in[3];
    const float* bn1_b = (const float*)d_in[4];
    const float* bn1_m = (const float*)d_in[5];
    const float* bn1_v = (const float*)d_in[6];
    const float* off_w = (const float*)d_in[7];
    const float* off_b = (const float*)d_in[8];
    const float* dcn_w = (const float*)d_in[9];
    const float* dcn_b = (const float*)d_in[10];
    const float* bn2_g = (const float*)d_in[11];
    const float* bn2_b = (const float*)d_in[12];
    const float* bn2_m = (const float*)d_in[13];
    const float* bn2_v = (const float*)d_in[14];

    // Workspace (float-slot offsets).
    float* ws = (float*)d_ws;
    short* Xpad   = (short*)ws;                 // 17,842,176 sh = 8,921,088 f
    float* offbuf = ws + 8921088;               //    884,736 f
    short* p1_wb  = (short*)(ws + 9805824);     //     65,536 sh = 32,768 f
    short* Woffb  = (short*)(ws + 9838592);     //    147,456 sh = 73,728 f
    short* Wbf    = (short*)(ws + 9912320);     //    589,824 sh = 294,912 f
    float* bias1f = ws + 10207232;              //        256
    float* inv2f  = ws + 10207488;              //        256
    float* bias2f = ws + 10207744;              //        256

    k_prep<<<2625, 256, 0, stream>>>(p1_w, p1_b, bn1_g, bn1_b, bn1_m, bn1_v,
                                     off_w, dcn_w, dcn_b, bn2_g, bn2_b, bn2_m, bn2_v,
                                     p1_wb, Woffb, Wbf, bias1f, inv2f, bias2f,
                                     (unsigned*)Xpad);
    k_featT<<<2048, 256, 0, stream>>>(feature, Xpad);
    k_projm<<<512, 512, 0, stream>>>(Xpad, p1_wb, bias1f);
    k_offm<<<512, 512, 0, stream>>>(Xpad, Woffb, off_b, offbuf);
    k_gemm<<<512, 512, 0, stream>>>(Xpad, Wbf, offbuf, inv2f, bias2f, (float*)d_out);
}